// Round 1
// 872.067 us; speedup vs baseline: 1.0119x; 1.0119x over previous
//
#include <hip/hip_runtime.h>
#include <hip/hip_bf16.h>

typedef unsigned short u16;
typedef unsigned int u32;
typedef __attribute__((ext_vector_type(8))) short short8;
typedef __attribute__((ext_vector_type(4))) float f32x4;

constexpr int SA     = 168;    // act row stride (bf16): 336 B
constexpr int BLK_E  = 64;     // edges per block
constexpr int NTHR   = 256;    // 4 waves = 2 M-groups x 2 N-groups (5/5 N-split)
constexpr int CHUNK  = 512;    // u16 elems per (ks,j) fragment chunk = 1 KB
constexpr int WSLOT  = 50 * CHUNK;              // 25600 elems per layer (5 ks x 10 j)
constexpr size_t WS_HDR   = 262144;             // weights header

// slice schedule: s=0 -> (L0,ks0); s=1..15 -> L1..L3 (5 ks each); s=16..20 -> L4
constexpr int Ls (int s) { return s == 0 ? 0 : (s <= 15 ? 1 + (s - 1) / 5 : 4); }
constexpr int Kss(int s) { return s == 0 ? 0 : (s <= 15 ? (s - 1) % 5 : s - 16); }

__device__ __forceinline__ u16 f2bf(float f) {  // RNE (prep only)
    union { float f; unsigned u; } c; c.f = f;
    return (u16)((c.u + 0x7fffu + ((c.u >> 16) & 1u)) >> 16);
}
__device__ __forceinline__ unsigned pk_bf16(float a, float b) {  // v_cvt_pk_bf16_f32
    float2 f; f.x = a; f.y = b;
    __hip_bfloat162 h = __float22bfloat162_rn(f);
    return *(unsigned*)&h;
}

// act k'-storage (5/5 N-split):
__device__ __forceinline__ int kperm(int kp) {
    if (kp < 64)  return (kp & 3) * 16 + (kp >> 2);
    if (kp < 128) { const int m = kp - 64; return (5 + (m & 3)) * 16 + (m >> 2); }
    if (kp < 144) return 4 * 16 + (kp - 128);
    if (kp < 160) return 9 * 16 + (kp - 144);
    return 1 << 30;
}

// ---- prep: weights -> fragment-ordered chunks, BIAS FOLDED IN --------------
__global__ void prep_all(const float* __restrict__ W0, const float* __restrict__ W1,
                         const float* __restrict__ W2, const float* __restrict__ W3,
                         const float* __restrict__ W4,
                         const float* __restrict__ B0, const float* __restrict__ B1,
                         const float* __restrict__ B2, const float* __restrict__ B3,
                         const float* __restrict__ B4,
                         u16* __restrict__ Wt)
{
    const int l = blockIdx.y;
    const float* W; const float* B; int DI, DO; bool perm;
    if      (l == 0) { W = W0; B = B0; DI = 13;  DO = 150; perm = false; }
    else if (l == 1) { W = W1; B = B1; DI = 150; DO = 150; perm = true;  }
    else if (l == 2) { W = W2; B = B2; DI = 150; DO = 150; perm = true;  }
    else if (l == 3) { W = W3; B = B3; DI = 150; DO = 150; perm = true;  }
    else             { W = W4; B = B4; DI = 150; DO = 50;  perm = true;  }
    const int kbias = (l == 0) ? 13 : 150;      // constant-1 input row
    u16* dst = Wt + (size_t)l * WSLOT;
    for (int idx = blockIdx.x * blockDim.x + threadIdx.x; idx < WSLOT;
         idx += gridDim.x * blockDim.x) {
        const int chunk = idx / CHUNK;            // = ks*10 + j
        const int within = idx - chunk * CHUNK;
        const int lane = within >> 3, e = within & 7;
        const int ks = chunk / 10, j = chunk - ks * 10;
        const int c = lane & 15, q = lane >> 4;
        const int n = j * 16 + c;
        const int kphys = ks * 32 + q * 8 + e;
        const int klog = perm ? kperm(kphys) : kphys;
        float v = 0.f;
        if (n < DO) {
            if (klog < DI)          v = W[klog * DO + n];
            else if (klog == kbias) v = B[n];     // folded bias row
        }
        dst[idx] = f2bf(v);
    }
}

// ---- B-load for slice s (plain global->VGPR, coalesced 1 KB chunks) --------
__device__ __forceinline__ void loadB(const u16* __restrict__ Wt, int s,
                                      int ng, int lane, short8 (&slot)[5])
{
    const int l = Ls(s), ks = Kss(s);
    const int jb = (l < 4) ? ng * 5 : 0;
    const int nt = (l < 4) ? 5 : 4;
    const u16* base = Wt + (size_t)l * WSLOT + (size_t)(ks * 10 + jb) * CHUNK + lane * 8;
#pragma unroll
    for (int jj = 0; jj < 5; ++jj)
        if (jj < nt) slot[jj] = *(const short8*)&base[jj * CHUNK];
}

// ---- epilogue: relu + packed bf16, k'-permuted in-place store --------------
__device__ __forceinline__ void epilogue(u16* act, int mg, int ng, int col, int quad,
                                         f32x4 (&acc)[2][5])
{
#pragma unroll
    for (int mtl = 0; mtl < 2; ++mtl)
#pragma unroll
        for (int r = 0; r < 4; ++r) {
            u16* row = &act[((mg * 2 + mtl) * 16 + quad * 4 + r) * SA];
            uint2 pk;
            pk.x = pk_bf16(fmaxf(acc[mtl][0][r], 0.f), fmaxf(acc[mtl][1][r], 0.f));
            pk.y = pk_bf16(fmaxf(acc[mtl][2][r], 0.f), fmaxf(acc[mtl][3][r], 0.f));
            *(uint2*)&row[ng * 64 + col * 4] = pk;                 // tiles 0-3 / 5-8
            u16 sv = (u16)pk_bf16(fmaxf(acc[mtl][4][r], 0.f), 0.f);
            if (ng == 1 && col == 6) sv = 0x3F80;                  // n=150 := 1.0
            row[128 + ng * 16 + col] = sv;                         // tile 4 / 9
        }
}

// ====================== counting sort of edges by tgt =======================
__global__ void hist_kernel(const int* __restrict__ tgt, u32* __restrict__ cnt,
                            int n_edges)
{
    const int e = blockIdx.x * blockDim.x + threadIdx.x;
    if (e < n_edges) atomicAdd(&cnt[tgt[e]], 1u);
}

// per-block exclusive scan (Hillis-Steele), 256 elems/block
__global__ void scan1_kernel(const u32* __restrict__ cnt, u32* __restrict__ offs,
                             u32* __restrict__ bsum, int n)
{
    __shared__ u32 s[256];
    const int i = blockIdx.x * 256 + threadIdx.x;
    const u32 v = (i < n) ? cnt[i] : 0u;
    s[threadIdx.x] = v; __syncthreads();
#pragma unroll
    for (int d = 1; d < 256; d <<= 1) {
        const u32 t = (threadIdx.x >= d) ? s[threadIdx.x - d] : 0u;
        __syncthreads();
        s[threadIdx.x] += t;
        __syncthreads();
    }
    if (i < n) offs[i] = s[threadIdx.x] - v;         // exclusive within block
    if (threadIdx.x == 255) bsum[blockIdx.x] = s[255];
}

__global__ void scan2_kernel(u32* __restrict__ bsum, int nb)   // nb <= 512
{
    __shared__ u32 s[512];
    const int i = threadIdx.x;
    const u32 v = (i < nb) ? bsum[i] : 0u;
    s[i] = v; __syncthreads();
#pragma unroll
    for (int d = 1; d < 512; d <<= 1) {
        const u32 t = (i >= d) ? s[i - d] : 0u;
        __syncthreads();
        s[i] += t;
        __syncthreads();
    }
    if (i < nb) bsum[i] = s[i] - v;                  // exclusive block bases
}

__global__ void scan3_kernel(u32* __restrict__ offs, const u32* __restrict__ bsum,
                             u32* __restrict__ cursor, int n, int n_edges)
{
    const int i = blockIdx.x * 256 + threadIdx.x;
    if (i < n) {
        const u32 o = offs[i] + bsum[blockIdx.x];
        offs[i] = o;
        cursor[i] = o;
    }
    if (blockIdx.x == 0 && threadIdx.x == 0) offs[n] = (u32)n_edges;
}

__global__ void perm_kernel(const int* __restrict__ src, const int* __restrict__ tgt,
                            u32* __restrict__ cursor,
                            int* __restrict__ src_perm, int* __restrict__ tgt_perm,
                            int n_edges)
{
    const int e = blockIdx.x * blockDim.x + threadIdx.x;
    if (e < n_edges) {
        const int g = tgt[e];
        const u32 pos = atomicAdd(&cursor[g], 1u);
        src_perm[pos] = src[e];
        tgt_perm[pos] = g;
    }
}

// ------------------------------- Edge kernel --------------------------------
// Edges are SORTED BY TGT: each block's 64 edges form ~3-5 runs of equal tgt.
// Scatter = in-LDS per-column run reduction + one fp32 atomic per (run,col):
// ~300 atomics/block instead of 3200 (15x fewer device-scope RMWs).
__global__ __launch_bounds__(NTHR, 4) void edge_kernel(
    const float* __restrict__ t, const float* __restrict__ x, const float* __restrict__ Ofx,
    const int* __restrict__ src, const int* __restrict__ tgt,
    const u16* __restrict__ Wt,
    float* __restrict__ Ep, int n_edges)
{
    __shared__ __align__(16) u16 act[BLK_E * SA];      // 21504 B (reused as f32 E-tile)
    __shared__ int tgt_s[BLK_E];                       // 256 B

    const int tid  = threadIdx.x;
    const int lane = tid & 63;
    const int wv   = tid >> 6;
    const int mg   = wv >> 1;          // M-group: edges [mg*32, mg*32+32)
    const int ng   = wv & 1;           // N-group: tiles [ng*5, ng*5+5)
    const int col  = lane & 15;
    const int quad = lane >> 4;

    short8 Bwin[3][5];
    loadB(Wt, 0, ng, lane, Bwin[0]);    // prologue: 3-deep lookahead
    loadB(Wt, 1, ng, lane, Bwin[1]);
    loadB(Wt, 2, ng, lane, Bwin[2]);

    // ---- gather R' (tid<64; k=13 is the constant-1 bias column for L0) ----
    if (tid < BLK_E) {
        const int e = tid;
        const long long ge = (long long)blockIdx.x * BLK_E + e;
        const bool valid = ge < n_edges;
        const int s = valid ? src[ge] : 0;
        const int g = valid ? tgt[ge] : 0;
        const float4 xs = valid ? *(const float4*)&x[(size_t)s * 4] : float4{0, 0, 0, 0};
        const float2 os = valid ? *(const float2*)&Ofx[(size_t)s * 2] : float2{0, 0};
        const float4 xg = valid ? *(const float4*)&x[(size_t)g * 4] : float4{0, 0, 0, 0};
        const float2 og = valid ? *(const float2*)&Ofx[(size_t)g * 2] : float2{0, 0};
        const float tv = valid ? t[0] : 0.f;
        uint4 w0, w1;
        w0.x = pk_bf16(xs.x, xs.y); w0.y = pk_bf16(xs.z, xs.w);
        w0.z = pk_bf16(os.x, os.y); w0.w = pk_bf16(xg.x, xg.y);
        w1.x = pk_bf16(xg.z, xg.w); w1.y = pk_bf16(og.x, og.y);
        w1.z = pk_bf16(tv, 1.0f);   w1.w = 0u;     // k=13 := 1 (bias neuron)
        u16* row = &act[e * SA];
        *(uint4*)&row[0]  = w0;
        *(uint4*)&row[8]  = w1;
        *(uint4*)&row[16] = uint4{0, 0, 0, 0};
        *(uint4*)&row[24] = uint4{0, 0, 0, 0};
        tgt_s[e] = valid ? g : -1;
    }
    __syncthreads();

    f32x4 acc[2][5];
    short8 Af[2];

    // ---- s=0: L0 (K=32) ----
#pragma unroll
    for (int mtl = 0; mtl < 2; ++mtl)
#pragma unroll
        for (int jj = 0; jj < 5; ++jj) acc[mtl][jj] = f32x4{0.f, 0.f, 0.f, 0.f};
#pragma unroll
    for (int mtl = 0; mtl < 2; ++mtl)
        Af[mtl] = *(const short8*)&act[((mg * 2 + mtl) * 16 + col) * SA + quad * 8];
#pragma unroll
    for (int jj = 0; jj < 5; ++jj)
#pragma unroll
        for (int mtl = 0; mtl < 2; ++mtl)
            acc[mtl][jj] = __builtin_amdgcn_mfma_f32_16x16x32_bf16(
                Af[mtl], Bwin[0][jj], acc[mtl][jj], 0, 0, 0);
    loadB(Wt, 3, ng, lane, Bwin[0]);       // refill slot 0 (s=3)
    __syncthreads();                        // A-reads done
    epilogue(act, mg, ng, col, quad, acc);
    __syncthreads();                        // epilogue visible

    // ---- s=1..15: L1..L3 ----
#pragma unroll
    for (int s = 1; s <= 15; ++s) {
        const int ks = (s - 1) % 5;
        const int slot = s % 3;
        if (ks == 0) {
#pragma unroll
            for (int mtl = 0; mtl < 2; ++mtl)
#pragma unroll
                for (int jj = 0; jj < 5; ++jj) acc[mtl][jj] = f32x4{0.f, 0.f, 0.f, 0.f};
        }
#pragma unroll
        for (int mtl = 0; mtl < 2; ++mtl)
            Af[mtl] = *(const short8*)&act[((mg * 2 + mtl) * 16 + col) * SA
                                           + ks * 32 + quad * 8];
#pragma unroll
        for (int jj = 0; jj < 5; ++jj)
#pragma unroll
            for (int mtl = 0; mtl < 2; ++mtl)
                acc[mtl][jj] = __builtin_amdgcn_mfma_f32_16x16x32_bf16(
                    Af[mtl], Bwin[slot][jj], acc[mtl][jj], 0, 0, 0);
        if (s + 3 <= 20) loadB(Wt, s + 3, ng, lane, Bwin[slot]);
        if (ks == 4) {
            __syncthreads();                // all A-reads of layer done
            epilogue(act, mg, ng, col, quad, acc);
            __syncthreads();                // epilogue visible
        }
    }

    // ---- s=16..20: L4 — one M-tile per wave (mt = 2mg+ng), full N=4 --------
    const int mt4 = mg * 2 + ng;
    f32x4 acc4[4];
#pragma unroll
    for (int jj = 0; jj < 4; ++jj) acc4[jj] = f32x4{0.f, 0.f, 0.f, 0.f};
#pragma unroll
    for (int s = 16; s <= 20; ++s) {
        const int ks = s - 16;
        const int slot = s % 3;
        const short8 A4 = *(const short8*)&act[(mt4 * 16 + col) * SA
                                               + ks * 32 + quad * 8];
#pragma unroll
        for (int jj = 0; jj < 4; ++jj)
            acc4[jj] = __builtin_amdgcn_mfma_f32_16x16x32_bf16(
                A4, Bwin[slot][jj], acc4[jj], 0, 0, 0);
        if (s + 3 <= 20) loadB(Wt, s + 3, ng, lane, Bwin[slot]);  // refill 19,20
    }

    // ---- segment-reduced scatter (edges sorted by tgt) ---------------------
    __syncthreads();                        // all L4 A-reads of act done
    float* actF = (float*)act;              // reuse act LDS as f32 [64][52]
#pragma unroll
    for (int jj = 0; jj < 4; ++jj) {
        const int n = jj * 16 + col;
        if (n < 50) {
#pragma unroll
            for (int r = 0; r < 4; ++r)
                actF[(mt4 * 16 + quad * 4 + r) * 52 + n] = acc4[jj][r];
        }
    }
    __syncthreads();                        // E tile visible
    // 100 threads: (half h, col c). Scan 32 sorted rows, one atomic per run.
    if (tid < 100) {
        const int h = tid / 50;
        const int c = tid - h * 50;
        int   cur = tgt_s[h * 32];
        float a   = 0.f;
        for (int r = h * 32; r < h * 32 + 32; ++r) {
            const int   g = tgt_s[r];
            const float v = actF[r * 52 + c];
            if (g != cur) {
                if (cur >= 0) atomicAdd(&Ep[(size_t)cur * 50 + c], a);
                a = 0.f; cur = g;
            }
            a += v;
        }
        if (cur >= 0) atomicAdd(&Ep[(size_t)cur * 50 + c], a);
    }
}

// ---------------- Node kernel: fO MLP (fp32 VALU) ---------------------------
template<int DI, int DO, bool RELU>
__device__ __forceinline__ void mlp_layer_t(
    const float* __restrict__ W, const float* __restrict__ B,
    float (*in)[64], float (*out)[64], int tid)
{
    const int et = tid & 15;
    const int jt = tid >> 4;
    constexpr int NG = (DO + 15) / 16;

    float acc0[NG], acc1[NG], acc2[NG], acc3[NG];
#pragma unroll
    for (int g = 0; g < NG; ++g) {
        const int j = jt + 16 * g;
        const float bb = (j < DO) ? B[j] : 0.f;
        acc0[g] = bb; acc1[g] = bb; acc2[g] = bb; acc3[g] = bb;
    }
    for (int k = 0; k < DI; ++k) {
        const float4 a = *(const float4*)&in[k][et * 4];
#pragma unroll
        for (int g = 0; g < NG; ++g) {
            const int j = jt + 16 * g;
            const float wv = (j < DO) ? W[k * DO + j] : 0.f;
            acc0[g] = fmaf(a.x, wv, acc0[g]);
            acc1[g] = fmaf(a.y, wv, acc1[g]);
            acc2[g] = fmaf(a.z, wv, acc2[g]);
            acc3[g] = fmaf(a.w, wv, acc3[g]);
        }
    }
#pragma unroll
    for (int g = 0; g < NG; ++g) {
        const int j = jt + 16 * g;
        if (j < DO) {
            float4 v; v.x = acc0[g]; v.y = acc1[g]; v.z = acc2[g]; v.w = acc3[g];
            if (RELU) {
                v.x = fmaxf(v.x, 0.f); v.y = fmaxf(v.y, 0.f);
                v.z = fmaxf(v.z, 0.f); v.w = fmaxf(v.w, 0.f);
            }
            *(float4*)&out[j][et * 4] = v;
        }
    }
}

__global__ __launch_bounds__(256, 2) void node_kernel(
    const float* __restrict__ Ep, int ncopies, size_t copy_elems,
    const float* __restrict__ W0, const float* __restrict__ B0,
    const float* __restrict__ W1, const float* __restrict__ B1,
    float* __restrict__ P, int n_nodes)
{
    __shared__ float bufA[104][64];
    __shared__ float bufB[104][64];
    const int tid = threadIdx.x;
    const int n0  = blockIdx.x * 64;

    for (int idx = tid; idx < 64 * 50; idx += 256) {
        const int e = idx / 50;
        const int k = idx - e * 50;
        const int n = n0 + e;
        float s = 0.f;
        if (n < n_nodes) {
            const float* p = &Ep[(size_t)n * 50 + k];
            for (int c = 0; c < ncopies; ++c) s += p[(size_t)c * copy_elems];
        }
        bufA[k][e] = s;
    }
    __syncthreads();
    mlp_layer_t<50, 100, true >(W0, B0, bufA, bufB, tid); __syncthreads();
    mlp_layer_t<100, 4, false>(W1, B1, bufB, bufA, tid); __syncthreads();
    for (int idx = tid; idx < 64 * 4; idx += 256) {
        const int e = idx & 63;
        const int j = idx >> 6;
        const int n = n0 + e;
        if (n < n_nodes) P[(size_t)n * 4 + j] = bufA[j][e];
    }
}

// ------------------------------- launcher -----------------------------------
extern "C" void kernel_launch(void* const* d_in, const int* in_sizes, int n_in,
                              void* d_out, int out_size, void* d_ws, size_t ws_size,
                              hipStream_t stream)
{
    const float* t   = (const float*)d_in[0];
    const float* x   = (const float*)d_in[1];
    const float* Ofx = (const float*)d_in[2];
    const int*   src = (const int*)d_in[3];
    const int*   tgt = (const int*)d_in[4];
    const float* W0  = (const float*)d_in[5];  const float* B0 = (const float*)d_in[6];
    const float* W1  = (const float*)d_in[7];  const float* B1 = (const float*)d_in[8];
    const float* W2  = (const float*)d_in[9];  const float* B2 = (const float*)d_in[10];
    const float* W3  = (const float*)d_in[11]; const float* B3 = (const float*)d_in[12];
    const float* W4  = (const float*)d_in[13]; const float* B4 = (const float*)d_in[14];
    const float* OW0 = (const float*)d_in[15]; const float* OB0 = (const float*)d_in[16];
    const float* OW1 = (const float*)d_in[17]; const float* OB1 = (const float*)d_in[18];

    const int n_nodes = in_sizes[1] / 4;
    const int n_edges = in_sizes[3];

    // workspace layout (all 256-B aligned); total ~37.3 MB (old version used 40.3)
    auto align256 = [](size_t v) { return (v + 255) & ~(size_t)255; };
    char* ws = (char*)d_ws;
    const size_t copy_elems = (size_t)n_nodes * 50;
    size_t o = 0;
    u16*   Wt       = (u16*)(ws + o);  o = WS_HDR;
    float* Ep       = (float*)(ws + o); o = align256(o + copy_elems * sizeof(float));
    u32*   offs     = (u32*)(ws + o);  o = align256(o + (size_t)(n_nodes + 1) * 4);
    u32*   cursor   = (u32*)(ws + o);  o = align256(o + (size_t)n_nodes * 4);  // also hist cnt
    u32*   bsum     = (u32*)(ws + o);  o = align256(o + 512 * 4);
    int*   src_perm = (int*)(ws + o);  o = align256(o + (size_t)n_edges * 4);
    int*   tgt_perm = (int*)(ws + o);  o = align256(o + (size_t)n_edges * 4);

    const int NB  = (n_nodes + 255) / 256;          // 391 for 100K (scan2 handles <=512)
    const int EBK = (n_edges + 255) / 256;

    prep_all<<<dim3(32, 5), 256, 0, stream>>>(W0, W1, W2, W3, W4,
                                              B0, B1, B2, B3, B4, Wt);
    hipMemsetAsync(Ep, 0, copy_elems * sizeof(float), stream);
    hipMemsetAsync(cursor, 0, (size_t)n_nodes * 4, stream);

    // counting sort of edges by tgt
    hist_kernel <<<EBK, 256, 0, stream>>>(tgt, cursor, n_edges);
    scan1_kernel<<<NB, 256, 0, stream>>>(cursor, offs, bsum, n_nodes);
    scan2_kernel<<<1, 512, 0, stream>>>(bsum, NB);
    scan3_kernel<<<NB, 256, 0, stream>>>(offs, bsum, cursor, n_nodes, n_edges);
    perm_kernel <<<EBK, 256, 0, stream>>>(src, tgt, cursor, src_perm, tgt_perm, n_edges);

    edge_kernel<<<(n_edges + BLK_E - 1) / BLK_E, NTHR, 0, stream>>>(
        t, x, Ofx, src_perm, tgt_perm, Wt, Ep, n_edges);

    node_kernel<<<(n_nodes + 63) / 64, 256, 0, stream>>>(
        Ep, 1, copy_elems, OW0, OB0, OW1, OB1, (float*)d_out, n_nodes);
}